// Round 1
// baseline (53.679 us; speedup 1.0000x reference)
//
#include <hip/hip_runtime.h>
#include <math.h>

#define Bdim 16
#define Cdim 512
#define Ldim 4096
#define Gdim 32
#define CPG  16
#define HALF 8
#define EPSV 1e-5f

#define THREADS 512
#define NWAVES  (THREADS / 64)

__device__ __forceinline__ float wave_reduce_sum(float v) {
#pragma unroll
    for (int off = 32; off > 0; off >>= 1)
        v += __shfl_xor(v, off, 64);
    return v;
}

__device__ __forceinline__ float sigmoidf_(float x) {
    return 1.0f / (1.0f + expf(-x));
}

__global__ __launch_bounds__(THREADS, 4) void fused_ham_kernel(
    const float* __restrict__ x,
    const float* __restrict__ cw_w, const float* __restrict__ cw_b,
    const float* __restrict__ sw_w, const float* __restrict__ sw_b,
    const float* __restrict__ gn_w, const float* __restrict__ gn_b,
    float* __restrict__ out)
{
    const int bg   = blockIdx.x;          // 0 .. B*G-1
    const int b    = bg / Gdim;
    const int g    = bg % Gdim;
    const int tid  = threadIdx.x;
    const int wave = tid >> 6;
    const int lane = tid & 63;

    __shared__ float red1[NWAVES][HALF];
    __shared__ float red2[NWAVES][2];

    // input base for this (b,g): channels g*CPG + [0..15]
    const float* xb   = x + ((size_t)b * Cdim + (size_t)g * CPG) * Ldim;
    float*       outb = out + (size_t)b * Cdim * Ldim;

    const int l0 = tid * 4;               // float4 aligned; j=0 -> l0, j=1 -> l0+2048

    // ---------------- Phase A: x1 (channels 0..7) ----------------
    float4 a[HALF][2];
    float  s1[HALF];
#pragma unroll
    for (int c = 0; c < HALF; ++c) {
        s1[c] = 0.f;
#pragma unroll
        for (int j = 0; j < 2; ++j) {
            const float4 v = *reinterpret_cast<const float4*>(
                xb + (size_t)c * Ldim + j * (Ldim / 2) + l0);
            a[c][j] = v;
            s1[c] += (v.x + v.y) + (v.z + v.w);
        }
    }
#pragma unroll
    for (int c = 0; c < HALF; ++c) {
        const float t = wave_reduce_sum(s1[c]);
        if (lane == 0) red1[wave][c] = t;
    }
    __syncthreads();

    float w1[HALF];
    {
        const float cww = cw_w[g], cwb = cw_b[g];
#pragma unroll
        for (int c = 0; c < HALF; ++c) {
            float s = 0.f;
#pragma unroll
            for (int w = 0; w < NWAVES; ++w) s += red1[w][c];
            const float ca = s * (1.0f / Ldim);
            w1[c] = sigmoidf_(ca * cww + cwb);
        }
    }

    // write x1e: out channel = c*G + g
#pragma unroll
    for (int c = 0; c < HALF; ++c) {
        float* o = outb + (size_t)(c * Gdim + g) * Ldim;
#pragma unroll
        for (int j = 0; j < 2; ++j) {
            float4 v = a[c][j];
            v.x *= w1[c]; v.y *= w1[c]; v.z *= w1[c]; v.w *= w1[c];
            *reinterpret_cast<float4*>(o + j * (Ldim / 2) + l0) = v;
        }
    }

    // ---------------- Phase B: x2 (channels 8..15) ----------------
    float4 bb[HALF][2];
    float  sum = 0.f, ssq = 0.f;
#pragma unroll
    for (int c = 0; c < HALF; ++c) {
#pragma unroll
        for (int j = 0; j < 2; ++j) {
            const float4 v = *reinterpret_cast<const float4*>(
                xb + (size_t)(HALF + c) * Ldim + j * (Ldim / 2) + l0);
            bb[c][j] = v;
            sum += (v.x + v.y) + (v.z + v.w);
            ssq += (v.x * v.x + v.y * v.y) + (v.z * v.z + v.w * v.w);
        }
    }
    sum = wave_reduce_sum(sum);
    ssq = wave_reduce_sum(ssq);
    if (lane == 0) { red2[wave][0] = sum; red2[wave][1] = ssq; }
    __syncthreads();

    float tsum = 0.f, tssq = 0.f;
#pragma unroll
    for (int w = 0; w < NWAVES; ++w) { tsum += red2[w][0]; tssq += red2[w][1]; }
    const float inv_n = 1.0f / (HALF * Ldim);
    const float mu    = tsum * inv_n;
    const float var   = tssq * inv_n - mu * mu;
    const float rs    = rsqrtf(var + EPSV);

    float gw[HALF];
    float sgw = 0.f, mgb = 0.f;
#pragma unroll
    for (int c = 0; c < HALF; ++c) {
        gw[c] = gn_w[g * HALF + c];
        sgw  += gw[c];
        mgb  += gn_b[g * HALF + c];
    }
    mgb *= (1.0f / HALF);
    const float sww = sw_w[g], swb = sw_b[g];

#pragma unroll
    for (int j = 0; j < 2; ++j) {
        float4 ws; ws.x = 0.f; ws.y = 0.f; ws.z = 0.f; ws.w = 0.f;
#pragma unroll
        for (int c = 0; c < HALF; ++c) {
            ws.x += gw[c] * bb[c][j].x;
            ws.y += gw[c] * bb[c][j].y;
            ws.z += gw[c] * bb[c][j].z;
            ws.w += gw[c] * bb[c][j].w;
        }
        const float k0 = rs * (1.0f / HALF);
        const float koff = -mu * sgw;     // (ws + koff) * k0 + mgb  == sm
        float4 w2;
        w2.x = sigmoidf_(((ws.x + koff) * k0 + mgb) * sww + swb);
        w2.y = sigmoidf_(((ws.y + koff) * k0 + mgb) * sww + swb);
        w2.z = sigmoidf_(((ws.z + koff) * k0 + mgb) * sww + swb);
        w2.w = sigmoidf_(((ws.w + koff) * k0 + mgb) * sww + swb);

#pragma unroll
        for (int c = 0; c < HALF; ++c) {
            float* o = outb + (size_t)((HALF + c) * Gdim + g) * Ldim;
            float4 v = bb[c][j];
            v.x *= w2.x; v.y *= w2.y; v.z *= w2.z; v.w *= w2.w;
            *reinterpret_cast<float4*>(o + j * (Ldim / 2) + l0) = v;
        }
    }
}

extern "C" void kernel_launch(void* const* d_in, const int* in_sizes, int n_in,
                              void* d_out, int out_size, void* d_ws, size_t ws_size,
                              hipStream_t stream) {
    const float* x    = (const float*)d_in[0];
    const float* cw_w = (const float*)d_in[1];
    const float* cw_b = (const float*)d_in[2];
    const float* sw_w = (const float*)d_in[3];
    const float* sw_b = (const float*)d_in[4];
    const float* gn_w = (const float*)d_in[5];
    const float* gn_b = (const float*)d_in[6];
    float* out = (float*)d_out;

    fused_ham_kernel<<<dim3(Bdim * Gdim), dim3(THREADS), 0, stream>>>(
        x, cw_w, cw_b, sw_w, sw_b, gn_w, gn_b, out);
}